// Round 2
// baseline (571.835 us; speedup 1.0000x reference)
//
#include <hip/hip_runtime.h>
#include <hip/hip_bf16.h>
#include <stdint.h>

// Balanced grouped GEMM: G=8, each X_g[2048x2048] @ W_g[2048x2048]^T
#define NGROUPS 8
#define KDIM    2048   // in_features
#define NDIM    2048   // out_features
#define TPG     2048   // tokens per group

#define BM 128
#define BN 128
#define BK 32

typedef __attribute__((ext_vector_type(8))) short bf16x8;  // 8 bf16 = 4 VGPRs
typedef __attribute__((ext_vector_type(4))) float f32x4;

// fp32 -> bf16 bits, round-to-nearest-even (inputs contain no NaN)
__device__ __forceinline__ short f2b(float f) {
    union { float f; uint32_t u; } c; c.f = f;
    uint32_t u = c.u + 0x7FFFu + ((c.u >> 16) & 1u);
    return (short)(u >> 16);
}

// Decide device storage dtype of X: bf16 (flag=1) or fp32 (flag=0).
// Low 16 bits of each 32-bit word: for bf16 storage this is a full bf16 value
// of ~N(0,1) -> exponent field in [100,140] essentially always; for fp32
// storage these are mantissa bits -> exponent field uniform (~16% hit rate).
__global__ void detect_dtype_kernel(const uint32_t* __restrict__ x, int* __restrict__ flag)
{
    if (blockIdx.x == 0 && threadIdx.x == 0) {
        int cnt = 0;
        #pragma unroll 16
        for (int i = 0; i < 256; ++i) {
            uint32_t e = (x[i] >> 7) & 0xFFu;
            cnt += (e >= 100u && e <= 140u) ? 1 : 0;
        }
        *flag = (cnt >= 200) ? 1 : 0;
    }
}

__global__ __launch_bounds__(256)
void grouped_gemm(const void* __restrict__ Xv, const void* __restrict__ Wv,
                  void* __restrict__ Ov, const int* __restrict__ flagp)
{
    // bf16-bit tiles, row-major [row][k], row stride BK elems = 64 B
    __shared__ __align__(16) short As[BM * BK];
    __shared__ __align__(16) short Bs[BN * BK];

    const int isBf16 = flagp[0];   // uniform scalar

    const int tid = threadIdx.x;
    const int bx  = blockIdx.x;    // N tile
    const int by  = blockIdx.y;    // M tile
    const int g   = blockIdx.z;    // group

    // Staging map: thread t covers 8 contiguous k-elems of row (t>>2) and
    // row (t>>2)+64; chunk-in-row = t&3.
    const int srow = tid >> 2;
    const int scol = (tid & 3) * 8;

    const int lane = tid & 63;
    const int wave = tid >> 6;
    const int quad = lane >> 4;    // 0..3
    const int lr   = lane & 15;    // 0..15
    const int wm   = (wave >> 1) * 64;
    const int wn   = (wave & 1) * 64;

    const size_t xoff = ((size_t)g * TPG  + (size_t)by * BM) * KDIM + (size_t)srow * KDIM + scol;
    const size_t woff = ((size_t)g * NDIM + (size_t)bx * BN) * KDIM + (size_t)srow * KDIM + scol;

    f32x4 acc[4][4] = {};          // [mi][ni]

    for (int kt = 0; kt < KDIM; kt += BK) {
        bf16x8 a0, a1, b0, b1;
        if (isBf16) {
            const short* X = (const short*)Xv;
            const short* W = (const short*)Wv;
            const short* ga = X + xoff + kt;
            const short* gb = W + woff + kt;
            a0 = *(const bf16x8*)ga;
            a1 = *(const bf16x8*)(ga + (size_t)64 * KDIM);
            b0 = *(const bf16x8*)gb;
            b1 = *(const bf16x8*)(gb + (size_t)64 * KDIM);
        } else {
            const float* X = (const float*)Xv;
            const float* W = (const float*)Wv;
            const float* ga = X + xoff + kt;
            const float* gb = W + woff + kt;
            f32x4 fa0 = *(const f32x4*)ga, fa1 = *(const f32x4*)(ga + 4);
            f32x4 fa2 = *(const f32x4*)(ga + (size_t)64 * KDIM), fa3 = *(const f32x4*)(ga + (size_t)64 * KDIM + 4);
            f32x4 fb0 = *(const f32x4*)gb, fb1 = *(const f32x4*)(gb + 4);
            f32x4 fb2 = *(const f32x4*)(gb + (size_t)64 * KDIM), fb3 = *(const f32x4*)(gb + (size_t)64 * KDIM + 4);
            #pragma unroll
            for (int j = 0; j < 4; ++j) {
                a0[j] = f2b(fa0[j]); a0[j + 4] = f2b(fa1[j]);
                a1[j] = f2b(fa2[j]); a1[j + 4] = f2b(fa3[j]);
                b0[j] = f2b(fb0[j]); b0[j + 4] = f2b(fb1[j]);
                b1[j] = f2b(fb2[j]); b1[j + 4] = f2b(fb3[j]);
            }
        }

        __syncthreads();   // all reads of previous tile complete
        *(bf16x8*)&As[srow * BK + scol]        = a0;
        *(bf16x8*)&As[(srow + 64) * BK + scol] = a1;
        *(bf16x8*)&Bs[srow * BK + scol]        = b0;
        *(bf16x8*)&Bs[(srow + 64) * BK + scol] = b1;
        __syncthreads();   // tile visible

        // A-frag: A[m=lr(+off)][k=quad*8+j]; B-frag from W[n][k] rows (B^T input)
        bf16x8 af[4], bfr[4];
        #pragma unroll
        for (int i = 0; i < 4; ++i)
            af[i] = *(const bf16x8*)&As[(wm + i * 16 + lr) * BK + quad * 8];
        #pragma unroll
        for (int i = 0; i < 4; ++i)
            bfr[i] = *(const bf16x8*)&Bs[(wn + i * 16 + lr) * BK + quad * 8];

        #pragma unroll
        for (int mi = 0; mi < 4; ++mi)
            #pragma unroll
            for (int ni = 0; ni < 4; ++ni)
                acc[mi][ni] = __builtin_amdgcn_mfma_f32_16x16x32_bf16(
                    af[mi], bfr[ni], acc[mi][ni], 0, 0, 0);
    }

    // Epilogue. C/D layout (m89-verified): col = lane&15, row = quad*4 + reg.
    const size_t obase = ((size_t)g * TPG + (size_t)by * BM) * NDIM + (size_t)bx * BN;
    if (isBf16) {
        short* O = (short*)Ov;
        #pragma unroll
        for (int mi = 0; mi < 4; ++mi)
            #pragma unroll
            for (int r = 0; r < 4; ++r) {
                const int row = wm + mi * 16 + quad * 4 + r;
                #pragma unroll
                for (int ni = 0; ni < 4; ++ni)
                    O[obase + (size_t)row * NDIM + wn + ni * 16 + lr] = f2b(acc[mi][ni][r]);
            }
    } else {
        float* O = (float*)Ov;
        #pragma unroll
        for (int mi = 0; mi < 4; ++mi)
            #pragma unroll
            for (int r = 0; r < 4; ++r) {
                const int row = wm + mi * 16 + quad * 4 + r;
                #pragma unroll
                for (int ni = 0; ni < 4; ++ni)
                    O[obase + (size_t)row * NDIM + wn + ni * 16 + lr] = acc[mi][ni][r];
            }
    }
}

extern "C" void kernel_launch(void* const* d_in, const int* in_sizes, int n_in,
                              void* d_out, int out_size, void* d_ws, size_t ws_size,
                              hipStream_t stream) {
    const void* X = d_in[0];   // [16384, 2048]  (bf16 or fp32 — detected)
    const void* W = d_in[1];   // [8, 2048, 2048]
    int* flag = (int*)d_ws;

    detect_dtype_kernel<<<1, 64, 0, stream>>>((const uint32_t*)X, flag);

    dim3 grid(NDIM / BN, TPG / BM, NGROUPS);   // 16 x 16 x 8 = 2048 blocks
    grouped_gemm<<<grid, dim3(256), 0, stream>>>(X, W, d_out, flag);
}